// Round 3
// baseline (44.428 us; speedup 1.0000x reference)
//
#include <hip/hip_runtime.h>

#define N_NODES 4096
#define IN_DIM  128
#define OUT_DIM 32
#define HEADS   4
#define FDIM    128   // OUT_DIM*HEADS
#define K1_ROWS 8
#define CAPQ    64    // per-quarter edge capacity (mean 15.4, ~12 sigma headroom)

// ---------------- Kernel 1: xp = x@W ; s_i, s_j per (row, head) ----------------
__global__ __launch_bounds__(256) void gat_proj(const float* __restrict__ x,
                                                const float* __restrict__ W,
                                                const float* __restrict__ a,
                                                float* __restrict__ xp,
                                                float* __restrict__ sI,
                                                float* __restrict__ sJ) {
    __shared__ float xs[K1_ROWS * IN_DIM];   // 4 KB: x tile, then reused as xp tile
    const int t    = threadIdx.x;
    const int row0 = blockIdx.x * K1_ROWS;

    ((float4*)xs)[t] = ((const float4*)(x + (size_t)row0 * IN_DIM))[t];
    __syncthreads();

    const int c  = t & 127;          // output column
    const int rg = t >> 7;           // 0..1 -> rows rg*4 .. rg*4+3
    const float* xb = xs + (rg * 4) * IN_DIM;

    float acc0 = 0.f, acc1 = 0.f, acc2 = 0.f, acc3 = 0.f;
#pragma unroll 4
    for (int k0 = 0; k0 < IN_DIM; k0 += 4) {
        const float w0 = W[(k0 + 0) * FDIM + c];
        const float w1 = W[(k0 + 1) * FDIM + c];
        const float w2 = W[(k0 + 2) * FDIM + c];
        const float w3 = W[(k0 + 3) * FDIM + c];
        const float4 x0 = *(const float4*)(xb + 0 * IN_DIM + k0);
        const float4 x1 = *(const float4*)(xb + 1 * IN_DIM + k0);
        const float4 x2 = *(const float4*)(xb + 2 * IN_DIM + k0);
        const float4 x3 = *(const float4*)(xb + 3 * IN_DIM + k0);
        acc0 = fmaf(x0.x, w0, fmaf(x0.y, w1, fmaf(x0.z, w2, fmaf(x0.w, w3, acc0))));
        acc1 = fmaf(x1.x, w0, fmaf(x1.y, w1, fmaf(x1.z, w2, fmaf(x1.w, w3, acc1))));
        acc2 = fmaf(x2.x, w0, fmaf(x2.y, w1, fmaf(x2.z, w2, fmaf(x2.w, w3, acc2))));
        acc3 = fmaf(x3.x, w0, fmaf(x3.y, w1, fmaf(x3.z, w2, fmaf(x3.w, w3, acc3))));
    }

    const int rb = rg * 4;
    xp[(size_t)(row0 + rb + 0) * FDIM + c] = acc0;
    xp[(size_t)(row0 + rb + 1) * FDIM + c] = acc1;
    xp[(size_t)(row0 + rb + 2) * FDIM + c] = acc2;
    xp[(size_t)(row0 + rb + 3) * FDIM + c] = acc3;

    __syncthreads();                      // everyone done reading x tile
    xs[(rb + 0) * FDIM + c] = acc0;       // reuse LDS as xp tile
    xs[(rb + 1) * FDIM + c] = acc1;
    xs[(rb + 2) * FDIM + c] = acc2;
    xs[(rb + 3) * FDIM + c] = acc3;
    __syncthreads();

    if (t < K1_ROWS * HEADS) {            // 32 threads: (row, head) pairs
        const int r = t >> 2, h = t & 3;
        const float4* xr = (const float4*)(xs + r * FDIM + h * OUT_DIM);
        const float4* aj = (const float4*)a;             // a[:32]
        const float4* ai = (const float4*)(a + OUT_DIM); // a[32:]
        float vi = 0.f, vj = 0.f;
#pragma unroll
        for (int q = 0; q < 8; ++q) {
            const float4 xv = xr[q], a1 = ai[q], a0 = aj[q];
            vi += xv.x * a1.x + xv.y * a1.y + xv.z * a1.z + xv.w * a1.w;
            vj += xv.x * a0.x + xv.y * a0.y + xv.z * a0.z + xv.w * a0.w;
        }
        sI[(row0 + r) * HEADS + h] = vi;
        sJ[(row0 + r) * HEADS + h] = vj;
    }
}

// ---------------- Kernel 2: streaming scan -> global compacted edge lists ----
// One block per row; wave w ballot-compacts quarter w into elist[row][w][..].
// No LDS, no barriers: pure BW streaming.
__global__ __launch_bounds__(256) void gat_scan(const float* __restrict__ adj,
                                                int* __restrict__ ecnt,
                                                int* __restrict__ elist) {
    const int i    = blockIdx.x;
    const int wv   = threadIdx.x >> 6;
    const int lane = threadIdx.x & 63;

    const float4* arow = (const float4*)(adj + (size_t)i * N_NODES) + wv * 256;
    const float4 v0 = arow[lane];
    const float4 v1 = arow[64 + lane];
    const float4 v2 = arow[128 + lane];
    const float4 v3 = arow[192 + lane];

    const unsigned long long lt = (1ULL << lane) - 1ULL;
    int* seg = elist + ((size_t)i * 4 + wv) * CAPQ;
    int base = 0;
    const int cb = wv * 1024 + lane * 4;

#define COMPACT(val, col)                                                     \
    {                                                                         \
        const unsigned long long mk = __ballot((val) != 0.f);                 \
        const int pos = base + __popcll(mk & lt);                             \
        if ((val) != 0.f && pos < CAPQ) seg[pos] = (col);                     \
        base += __popcll(mk);                                                 \
    }
    COMPACT(v0.x, cb + 0)   COMPACT(v0.y, cb + 1)   COMPACT(v0.z, cb + 2)   COMPACT(v0.w, cb + 3)
    COMPACT(v1.x, cb + 256) COMPACT(v1.y, cb + 257) COMPACT(v1.z, cb + 258) COMPACT(v1.w, cb + 259)
    COMPACT(v2.x, cb + 512) COMPACT(v2.y, cb + 513) COMPACT(v2.z, cb + 514) COMPACT(v2.w, cb + 515)
    COMPACT(v3.x, cb + 768) COMPACT(v3.y, cb + 769) COMPACT(v3.z, cb + 770) COMPACT(v3.w, cb + 771)
#undef COMPACT

    if (lane == 0) ecnt[i * 4 + wv] = base;
}

// ---------------- Kernel 3: softmax + aggregate from compacted lists ---------
// One block (4 waves = 4 heads) per row. Tiny LDS -> high occupancy.
__global__ __launch_bounds__(256) void gat_agg(const float* __restrict__ adj,
                                               const float* __restrict__ xp,
                                               const float* __restrict__ sI,
                                               const float* __restrict__ sJ,
                                               const int* __restrict__ ecnt,
                                               const int* __restrict__ elist,
                                               float* __restrict__ out) {
    const int i    = blockIdx.x;
    const int tid  = threadIdx.x;
    const int lane = tid & 63;
    const int h    = tid >> 6;      // wave = head

    __shared__ int elist_s[4 * CAPQ];   // 1 KB (4*CAPQ == 256 == blockDim)
    __shared__ int cnts_s[4];

    if (tid < 4) cnts_s[tid] = ecnt[i * 4 + tid];
    elist_s[tid] = elist[(size_t)i * 4 * CAPQ + tid];
    __syncthreads();

    const int c0 = cnts_s[0], c1 = cnts_s[1], c2 = cnts_s[2], c3 = cnts_s[3];
    const float scale = 0.17677669529663687f;   // 1/sqrt(32)
    const float si = sI[i * HEADS + h];

    const bool ovf = (c0 > CAPQ) | (c1 > CAPQ) | (c2 > CAPQ) | (c3 > CAPQ);
    if (__builtin_expect(!ovf, 1)) {
        const int o1 = c0, o2 = c0 + c1, o3 = o2 + c2;
        const int nE = o3 + c3;

        // ---- online softmax stats across 64 lanes ----
        float m = -1e30f, Z = 0.f;
        for (int e = lane; e < nE; e += 64) {
            const int s3 = e >= o3, s2 = e >= o2, s1 = e >= o1;
            const int sg  = s1 + s2 + s3;
            const int sub = e - (s3 ? o3 : (s2 ? o2 : (s1 ? o1 : 0)));
            const int j = elist_s[sg * CAPQ + sub];
            const float ej = (si + sJ[j * HEADS + h]) * scale;
            const float mn = fmaxf(m, ej);
            Z = Z * __expf(m - mn) + __expf(ej - mn);
            m = mn;
        }
#pragma unroll
        for (int off = 32; off; off >>= 1) {
            const float m2 = __shfl_xor(m, off);
            const float Z2 = __shfl_xor(Z, off);
            const float mn = fmaxf(m, m2);
            Z = Z * __expf(m - mn) + Z2 * __expf(m2 - mn);
            m = mn;
        }

        // ---- float4 aggregation: lane = (edge-slot eg, dim-group d4) ----
        const int d4 = lane & 7, eg = lane >> 3;
        float ax = 0.f, ay = 0.f, az = 0.f, aw = 0.f;
        const float4* xp4 = (const float4*)xp;
        for (int e = eg; e < nE; e += 8) {
            const int s3 = e >= o3, s2 = e >= o2, s1 = e >= o1;
            const int sg  = s1 + s2 + s3;
            const int sub = e - (s3 ? o3 : (s2 ? o2 : (s1 ? o1 : 0)));
            const int j = elist_s[sg * CAPQ + sub];
            const float p = __expf(fmaf(si + sJ[j * HEADS + h], scale, -m));
            const float4 xv = xp4[j * (FDIM / 4) + h * (OUT_DIM / 4) + d4];
            ax = fmaf(p, xv.x, ax);
            ay = fmaf(p, xv.y, ay);
            az = fmaf(p, xv.z, az);
            aw = fmaf(p, xv.w, aw);
        }
#pragma unroll
        for (int off = 8; off < 64; off <<= 1) {
            ax += __shfl_xor(ax, off);
            ay += __shfl_xor(ay, off);
            az += __shfl_xor(az, off);
            aw += __shfl_xor(aw, off);
        }
        if (eg == 0) {
            const float inv = 1.0f / Z;
            float4 o;
            o.x = ax * inv; o.y = ay * inv; o.z = az * inv; o.w = aw * inv;
            ((float4*)out)[i * (FDIM / 4) + h * (OUT_DIM / 4) + d4] = o;
        }
    } else {
        // ---- exact fallback: flash-style streaming re-scan of this adj row ----
        // (statistically never taken at p=0.015; kept for correctness)
        float m = -1e30f, Z = 0.f;
        float acc[OUT_DIM];
#pragma unroll
        for (int d = 0; d < OUT_DIM; ++d) acc[d] = 0.f;
        for (int c = lane; c < N_NODES; c += 64) {
            const float av = adj[(size_t)i * N_NODES + c];
            if (av != 0.f) {
                const float ej = (si + sJ[c * HEADS + h]) * scale;
                const float mn = fmaxf(m, ej);
                const float r  = __expf(m - mn);
                const float p  = __expf(ej - mn);
                Z = Z * r + p;
                m = mn;
                const float* xr = xp + (size_t)c * FDIM + h * OUT_DIM;
#pragma unroll
                for (int d = 0; d < OUT_DIM; ++d) acc[d] = fmaf(p, xr[d], acc[d] * r);
            }
        }
#pragma unroll
        for (int off = 32; off; off >>= 1) {
            const float m2 = __shfl_xor(m, off);
            const float Z2 = __shfl_xor(Z, off);
            const float mn = fmaxf(m, m2);
            const float r1 = __expf(m - mn), r2 = __expf(m2 - mn);
            Z = Z * r1 + Z2 * r2;
            m = mn;
#pragma unroll
            for (int d = 0; d < OUT_DIM; ++d) {
                const float other = __shfl_xor(acc[d], off);
                acc[d] = acc[d] * r1 + other * r2;
            }
        }
        if (lane == 0) {
            const float inv = 1.0f / Z;
#pragma unroll
            for (int d = 0; d < OUT_DIM; ++d)
                out[i * FDIM + h * OUT_DIM + d] = acc[d] * inv;
        }
    }
}

extern "C" void kernel_launch(void* const* d_in, const int* in_sizes, int n_in,
                              void* d_out, int out_size, void* d_ws, size_t ws_size,
                              hipStream_t stream) {
    const float* x   = (const float*)d_in[0];
    const float* adj = (const float*)d_in[1];
    const float* W   = (const float*)d_in[2];
    const float* a   = (const float*)d_in[3];
    float* out = (float*)d_out;

    float* xp = (float*)d_ws;                    // 4096*128 f32 = 2 MB
    float* sI = xp + N_NODES * FDIM;             // 64 KB
    float* sJ = sI + N_NODES * HEADS;            // 64 KB
    int*  ecnt  = (int*)(sJ + N_NODES * HEADS);  // 64 KB
    int*  elist = ecnt + N_NODES * 4;            // 4096*4*64*4B = 4 MB

    gat_proj<<<N_NODES / K1_ROWS, 256, 0, stream>>>(x, W, a, xp, sI, sJ);
    gat_scan<<<N_NODES, 256, 0, stream>>>(adj, ecnt, elist);
    gat_agg<<<N_NODES, 256, 0, stream>>>(adj, xp, sI, sJ, ecnt, elist, out);
}